// Round 1
// baseline (102.706 us; speedup 1.0000x reference)
//
#include <hip/hip_runtime.h>

#define NB 32
#define NK 8
#define IN_DIM 512
#define DLAT 128
#define DTOT 1024

// Kernel 1: one block per batch b. Computes a[b,:] (normalized evolved state,
// pre-scaled so out = a_i*a_j + diag) and diag[b].
__global__ __launch_bounds__(256) void qsfm_setup(
    const float* __restrict__ z, const float* __restrict__ t,
    const float* __restrict__ W_proj, const float* __restrict__ b_proj,
    const float* __restrict__ W1, const float* __restrict__ b1,
    const float* __restrict__ W2, const float* __restrict__ b2,
    float* __restrict__ a_out, float* __restrict__ diag_out)
{
    __shared__ float psi[DTOT];     // psi, then state (in place)
    __shared__ float part[256];
    __shared__ float norm2[NK];
    __shared__ float stage16[16];
    __shared__ float f_s[8];
    __shared__ float lam_s;
    __shared__ float n2_s;

    const int b = blockIdx.x;
    const int tid = threadIdx.x;

    // ---- Phase A.1: psi[k,o] = W_proj[o,:] . z[b,k,:] + b_proj[o]
    for (int r = tid; r < DTOT; r += 256) {
        const int k = r >> 7, o = r & (DLAT - 1);
        const float4* __restrict__ wrow = (const float4*)(W_proj + o * IN_DIM);
        const float4* __restrict__ zrow = (const float4*)(z + (b * NK + k) * IN_DIM);
        float acc = 0.f;
        #pragma unroll 8
        for (int i = 0; i < IN_DIM / 4; ++i) {
            const float4 w = wrow[i], zz = zrow[i];
            acc += w.x * zz.x + w.y * zz.y + w.z * zz.z + w.w * zz.w;
        }
        psi[r] = acc + b_proj[o];
    }
    __syncthreads();

    // ---- per-shot L2 norm^2 (deterministic tree: 128 partials -> 8 sums)
    if (tid < 128) {
        const int k = tid >> 4, l = tid & 15;
        float s = 0.f;
        #pragma unroll
        for (int q = 0; q < 8; ++q) {
            const float v = psi[k * DLAT + l * 8 + q];
            s += v * v;
        }
        part[tid] = s;
    }
    __syncthreads();
    if (tid < NK) {
        float s = 0.f;
        #pragma unroll
        for (int q = 0; q < 16; ++q) s += part[tid * 16 + q];
        norm2[tid] = s;
    }
    __syncthreads();

    // ---- normalize each shot, scale by 1/sqrt(K): state in place
    for (int r = tid; r < DTOT; r += 256) {
        const float nrm = fmaxf(sqrtf(norm2[r >> 7]), 1e-8f);
        psi[r] = psi[r] / nrm * 0.35355339059327373f;  // 1/sqrt(8)
    }
    __syncthreads();

    // ---- lambda(t): Linear(1->128) -> SiLU -> Linear(128->1) -> tanh, *0.1
    if (tid < 128) {
        const float h = t[b] * W1[tid] + b1[tid];
        const float sil = h / (1.f + expf(-h));     // SiLU
        part[tid] = W2[tid] * sil;
    }
    __syncthreads();
    if (tid == 0) {
        float s = 0.f;
        for (int q = 0; q < 128; ++q) s += part[q];
        lam_s = tanhf(s + b2[0]) * 0.1f;
    }
    __syncthreads();

    // ---- E = exp(-lam * H_idx), H_idx = C8 cycle adjacency => symmetric
    //      circulant: E[k,k'] = f((k-k') mod 8),
    //      f(d) = 1/8 * sum_m exp(-2 lam cos(pi m/4)) cos(pi m d/4)
    if (tid < 8) {
        const float c4[8] = {1.f, 0.70710678118654752f, 0.f, -0.70710678118654752f,
                             -1.f, -0.70710678118654752f, 0.f, 0.70710678118654752f};
        const float lam = lam_s;
        float acc = 0.f;
        #pragma unroll
        for (int m = 0; m < 8; ++m)
            acc += expf(-2.f * lam * c4[m]) * c4[(m * tid) & 7];
        f_s[tid] = 0.125f * acc;
    }
    __syncthreads();

    // ---- y = kron(E, I_128) @ state, plus ||y||^2 partials
    float yv[4];
    float loc = 0.f;
    #pragma unroll
    for (int ii = 0; ii < 4; ++ii) {
        const int r = tid + ii * 256;
        const int k = r >> 7, o = r & (DLAT - 1);
        float acc = 0.f;
        #pragma unroll
        for (int kp = 0; kp < NK; ++kp)
            acc += f_s[(k - kp) & 7] * psi[kp * DLAT + o];
        yv[ii] = acc;
        loc += acc * acc;
    }
    part[tid] = loc;
    __syncthreads();
    if (tid < 16) {
        float s = 0.f;
        #pragma unroll
        for (int q = 0; q < 16; ++q) s += part[tid * 16 + q];
        stage16[tid] = s;
    }
    __syncthreads();
    if (tid == 0) {
        float s = 0.f;
        #pragma unroll
        for (int q = 0; q < 16; ++q) s += stage16[q];
        n2_s = s;
    }
    __syncthreads();

    // ---- epilogue algebra:
    // rho1 = y y^T / clip(n2);  rho2 = rho1 + 1e-7 I;  out = rho2 / tr(rho2)
    // => out[i][j] = a_i a_j + delta_ij * 1e-7/tr2,
    //    a = y / sqrt(n2c * tr2), tr2 = n2/n2c + 1024e-7
    const float n2 = n2_s;
    const float n2c = fmaxf(n2, 1e-8f);
    const float tr2 = n2 / n2c + (float)DTOT * 1e-7f;
    const float sc = 1.f / sqrtf(n2c * tr2);
    #pragma unroll
    for (int ii = 0; ii < 4; ++ii) {
        const int r = tid + ii * 256;
        a_out[b * DTOT + r] = yv[ii] * sc;
    }
    if (tid == 0) diag_out[b] = 1e-7f / tr2;
}

// Kernel 2: out[b,i,j] = a[b,i]*a[b,j] (+ diag[b] on the diagonal).
// Pure streaming write of 128 MB; a (128 KB) stays L2-resident.
__global__ __launch_bounds__(256) void qsfm_outer(
    const float* __restrict__ a, const float* __restrict__ diag,
    float4* __restrict__ out)
{
    const int total4 = NB * DTOT * (DTOT / 4);     // 8388608
    const int stride = gridDim.x * blockDim.x;
    for (int idx4 = blockIdx.x * blockDim.x + threadIdx.x; idx4 < total4;
         idx4 += stride) {
        const int j4 = idx4 & (DTOT / 4 - 1);      // float4 col
        const int i  = (idx4 >> 8) & (DTOT - 1);   // row
        const int b  = idx4 >> 18;                 // / (1024*256)
        const float ai = a[b * DTOT + i];
        const float4 aj = *(const float4*)(a + b * DTOT + j4 * 4);
        float4 v;
        v.x = ai * aj.x; v.y = ai * aj.y; v.z = ai * aj.z; v.w = ai * aj.w;
        const int dj = i - j4 * 4;
        if (dj >= 0 && dj < 4) {
            const float dd = diag[b];
            if      (dj == 0) v.x += dd;
            else if (dj == 1) v.y += dd;
            else if (dj == 2) v.z += dd;
            else              v.w += dd;
        }
        out[idx4] = v;
    }
}

extern "C" void kernel_launch(void* const* d_in, const int* in_sizes, int n_in,
                              void* d_out, int out_size, void* d_ws, size_t ws_size,
                              hipStream_t stream) {
    (void)in_sizes; (void)n_in; (void)out_size; (void)ws_size;
    const float* z  = (const float*)d_in[0];
    const float* t  = (const float*)d_in[1];
    const float* Wp = (const float*)d_in[2];
    const float* bp = (const float*)d_in[3];
    const float* W1 = (const float*)d_in[4];
    const float* b1 = (const float*)d_in[5];
    const float* W2 = (const float*)d_in[6];
    const float* b2 = (const float*)d_in[7];

    float* ws   = (float*)d_ws;
    float* a    = ws;              // NB*DTOT floats
    float* diag = ws + NB * DTOT;  // NB floats

    qsfm_setup<<<NB, 256, 0, stream>>>(z, t, Wp, bp, W1, b1, W2, b2, a, diag);
    qsfm_outer<<<2048, 256, 0, stream>>>(a, diag, (float4*)d_out);
}

// Round 2
// 44.826 us; speedup vs baseline: 2.2912x; 2.2912x over previous
//
#include <hip/hip_runtime.h>

#define NB 32
#define NK 8
#define IN_DIM 512
#define DLAT 128
#define DTOT 1024

// ---------------------------------------------------------------------------
// Kernel 1: projection + per-shot L2 normalize.  One block per shot (b,k).
// Wave-cooperative dot products: 64 lanes read 64 consecutive float4 of one
// W_proj row (1 KB coalesced), dot against LDS-staged z, shuffle-reduce.
// ---------------------------------------------------------------------------
__global__ __launch_bounds__(512) void qsfm_proj(
    const float* __restrict__ z, const float* __restrict__ W_proj,
    const float* __restrict__ b_proj, float* __restrict__ psi_out)
{
    __shared__ float4 z4[IN_DIM / 4];   // 512 floats of this shot's z
    __shared__ float psi_s[DLAT];
    __shared__ float part[64];
    __shared__ float n2_sh;

    const int shot = blockIdx.x;        // b*NK + k
    const int tid = threadIdx.x;

    if (tid < IN_DIM / 4)
        z4[tid] = ((const float4*)(z + (size_t)shot * IN_DIM))[tid];
    __syncthreads();

    const int w = tid >> 6;             // wave 0..7, each owns 16 outputs
    const int l = tid & 63;
    #pragma unroll 4
    for (int oi = 0; oi < 16; ++oi) {
        const int o = w * 16 + oi;
        const float4* __restrict__ wrow = (const float4*)(W_proj + (size_t)o * IN_DIM);
        const float4 wa = wrow[l], wb = wrow[64 + l];
        const float4 za = z4[l], zb = z4[64 + l];
        float acc = wa.x * za.x + wa.y * za.y + wa.z * za.z + wa.w * za.w;
        acc += wb.x * zb.x + wb.y * zb.y + wb.z * zb.z + wb.w * zb.w;
        #pragma unroll
        for (int s = 32; s; s >>= 1) acc += __shfl_xor(acc, s);
        if (l == 0) psi_s[o] = acc + b_proj[o];
    }
    __syncthreads();

    // ||psi||^2 over 128 outputs (deterministic tree)
    if (tid < 64) {
        const float va = psi_s[tid], vb = psi_s[tid + 64];
        part[tid] = va * va + vb * vb;
    }
    __syncthreads();
    if (tid < 64) {
        float s = part[tid];
        #pragma unroll
        for (int d = 32; d; d >>= 1) s += __shfl_xor(s, d);
        if (tid == 0) n2_sh = s;
    }
    __syncthreads();

    // normalize, pre-scale by 1/sqrt(K)
    if (tid < 128) {
        const float nrm = fmaxf(sqrtf(n2_sh), 1e-8f);
        psi_out[shot * DLAT + tid] = psi_s[tid] / nrm * 0.35355339059327373f;
    }
}

// ---------------------------------------------------------------------------
// Kernel 2: per-batch MLP -> circulant exp(-lam*H_idx) mix -> rank-1 epilogue
// constants.  One block per batch b (tiny).
// ---------------------------------------------------------------------------
__global__ __launch_bounds__(256) void qsfm_mix(
    const float* __restrict__ t,
    const float* __restrict__ W1, const float* __restrict__ b1,
    const float* __restrict__ W2, const float* __restrict__ b2,
    const float* __restrict__ psi_norm,
    float* __restrict__ a_out, float* __restrict__ diag_out)
{
    __shared__ float psi[DTOT];
    __shared__ float part[256];
    __shared__ float stage16[16];
    __shared__ float f_s[8];
    __shared__ float lam_sh;
    __shared__ float n2_sh;

    const int b = blockIdx.x;
    const int tid = threadIdx.x;

    // stage normalized state (1024 floats) + run the scalar MLP concurrently
    ((float4*)psi)[tid] = ((const float4*)(psi_norm + b * DTOT))[tid];
    if (tid < 128) {
        const float h = t[b] * W1[tid] + b1[tid];
        part[tid] = W2[tid] * (h / (1.f + expf(-h)));   // SiLU * W2
    }
    __syncthreads();
    if (tid == 0) {
        float s = 0.f;
        for (int q = 0; q < 128; ++q) s += part[q];
        lam_sh = tanhf(s + b2[0]) * 0.1f;
    }
    __syncthreads();

    // E = exp(-lam*H_idx): symmetric circulant, f(d) = 1/8 sum_m
    // exp(-2 lam cos(pi m/4)) cos(pi m d /4)
    if (tid < 8) {
        const float c4[8] = {1.f, 0.70710678118654752f, 0.f, -0.70710678118654752f,
                             -1.f, -0.70710678118654752f, 0.f, 0.70710678118654752f};
        const float lam = lam_sh;
        float acc = 0.f;
        #pragma unroll
        for (int m = 0; m < 8; ++m)
            acc += expf(-2.f * lam * c4[m]) * c4[(m * tid) & 7];
        f_s[tid] = 0.125f * acc;
    }
    __syncthreads();

    // y = kron(E, I_128) @ state  +  ||y||^2 partials
    float yv[4];
    float loc = 0.f;
    #pragma unroll
    for (int ii = 0; ii < 4; ++ii) {
        const int r = tid + ii * 256;
        const int k = r >> 7, o = r & (DLAT - 1);
        float acc = 0.f;
        #pragma unroll
        for (int kp = 0; kp < NK; ++kp)
            acc += f_s[(k - kp) & 7] * psi[kp * DLAT + o];
        yv[ii] = acc;
        loc += acc * acc;
    }
    part[tid] = loc;
    __syncthreads();
    if (tid < 16) {
        float s = 0.f;
        #pragma unroll
        for (int q = 0; q < 16; ++q) s += part[tid * 16 + q];
        stage16[tid] = s;
    }
    __syncthreads();
    if (tid == 0) {
        float s = 0.f;
        #pragma unroll
        for (int q = 0; q < 16; ++q) s += stage16[q];
        n2_sh = s;
    }
    __syncthreads();

    // out[i][j] = a_i a_j + delta_ij * 1e-7/tr2,
    // a = y / sqrt(n2c * tr2), tr2 = n2/n2c + 1024e-7
    const float n2 = n2_sh;
    const float n2c = fmaxf(n2, 1e-8f);
    const float tr2 = n2 / n2c + (float)DTOT * 1e-7f;
    const float sc = 1.f / sqrtf(n2c * tr2);
    #pragma unroll
    for (int ii = 0; ii < 4; ++ii) {
        const int r = tid + ii * 256;
        a_out[b * DTOT + r] = yv[ii] * sc;
    }
    if (tid == 0) diag_out[b] = 1e-7f / tr2;
}

// ---------------------------------------------------------------------------
// Kernel 3: out[b,i,j] = a[b,i]*a[b,j] (+ diag[b] on the diagonal).
// Pure streaming write of 128 MB; a (128 KB) stays L2-resident.
// ---------------------------------------------------------------------------
__global__ __launch_bounds__(256) void qsfm_outer(
    const float* __restrict__ a, const float* __restrict__ diag,
    float4* __restrict__ out)
{
    const int total4 = NB * DTOT * (DTOT / 4);     // 8388608
    const int stride = gridDim.x * blockDim.x;
    for (int idx4 = blockIdx.x * blockDim.x + threadIdx.x; idx4 < total4;
         idx4 += stride) {
        const int j4 = idx4 & (DTOT / 4 - 1);      // float4 col
        const int i  = (idx4 >> 8) & (DTOT - 1);   // row
        const int b  = idx4 >> 18;                 // / (1024*256)
        const float ai = a[b * DTOT + i];
        const float4 aj = *(const float4*)(a + b * DTOT + j4 * 4);
        float4 v;
        v.x = ai * aj.x; v.y = ai * aj.y; v.z = ai * aj.z; v.w = ai * aj.w;
        const int dj = i - j4 * 4;
        if (dj >= 0 && dj < 4) {
            const float dd = diag[b];
            if      (dj == 0) v.x += dd;
            else if (dj == 1) v.y += dd;
            else if (dj == 2) v.z += dd;
            else              v.w += dd;
        }
        out[idx4] = v;
    }
}

extern "C" void kernel_launch(void* const* d_in, const int* in_sizes, int n_in,
                              void* d_out, int out_size, void* d_ws, size_t ws_size,
                              hipStream_t stream) {
    (void)in_sizes; (void)n_in; (void)out_size; (void)ws_size;
    const float* z  = (const float*)d_in[0];
    const float* t  = (const float*)d_in[1];
    const float* Wp = (const float*)d_in[2];
    const float* bp = (const float*)d_in[3];
    const float* W1 = (const float*)d_in[4];
    const float* b1 = (const float*)d_in[5];
    const float* W2 = (const float*)d_in[6];
    const float* b2 = (const float*)d_in[7];

    float* ws       = (float*)d_ws;
    float* psi_norm = ws;                        // NB*NK*DLAT = 32768 floats
    float* a        = psi_norm + NB * DTOT;      // NB*DTOT floats
    float* diag     = a + NB * DTOT;             // NB floats

    qsfm_proj<<<NB * NK, 512, 0, stream>>>(z, Wp, bp, psi_norm);
    qsfm_mix<<<NB, 256, 0, stream>>>(t, W1, b1, W2, b2, psi_norm, a, diag);
    qsfm_outer<<<2048, 256, 0, stream>>>(a, diag, (float4*)d_out);
}